// Round 16
// baseline (194.535 us; speedup 1.0000x reference)
//
#include <hip/hip_runtime.h>
#include <math.h>

#define EPSF 0.3f
#define NPB 128      // nodes per row-bucket
#define SHB 7        // log2(NPB)
#define MAXNB 512    // max buckets (N <= 65536; packed-edge limit N < 65536)
#define CHUNK 4096   // edges per block in pack/binwrite
#define MAXSEG 8192  // LDS-staged edges per bucket in k_csr (avg ~4090)

typedef __attribute__((ext_vector_type(8))) short bf16x8;
typedef __attribute__((ext_vector_type(4))) float f32x4;

// ---------------- bf16 helpers ----------------
__device__ __forceinline__ uint32_t f2bf(float f) {
    uint32_t u = __float_as_uint(f);
    return (u + 0x7fffu + ((u >> 16) & 1u)) >> 16;  // RNE
}
__device__ __forceinline__ uint32_t pack2(float lo, float hi) {
    return f2bf(lo) | (f2bf(hi) << 16);
}
__device__ __forceinline__ float bflo(uint32_t u) { return __uint_as_float(u << 16); }
__device__ __forceinline__ float bfhi(uint32_t u) { return __uint_as_float(u & 0xffff0000u); }

// fast tanh: 1 - 2/(e^{2x}+1)
__device__ __forceinline__ float fast_tanh(float x) {
    float e = __expf(2.f * x);
    return 1.f - 2.f * __builtin_amdgcn_rcpf(e + 1.f);
}

__device__ __forceinline__ int edge_at(const int* ei, int is64, size_t idx) {
    if (is64) return (int)((const long long*)ei)[idx];
    return ei[idx];
}

__device__ __forceinline__ int detect_is64(const int* ei, int base, int E) {
    __shared__ int s_nz;
    if (threadIdx.x == 0) s_nz = 0;
    __syncthreads();
    int lim = min(512, E - base);
    int nz = 0;
    for (int t = threadIdx.x; t < lim; t += 256)
        nz |= (ei[2 * (size_t)(base + t) + 1] != 0);
    if (nz) atomicOr(&s_nz, 1);
    __syncthreads();
    return s_nz == 0;
}

// 512-entry inclusive scan in LDS (256 threads, 2 slots each)
__device__ __forceinline__ void scan512(int* s) {
    int t = threadIdx.x;
    for (int o = 1; o < MAXNB; o <<= 1) {
        int i2 = t + 256;
        int x1 = (t >= o) ? s[t - o] : 0;
        int x2 = (i2 >= o) ? s[i2 - o] : 0;
        __syncthreads();
        s[t] += x1;
        s[i2] += x2;
        __syncthreads();
    }
}

// ---------------- pack + bucket histogram ----------------
__global__ __launch_bounds__(256) void k_pack(const int* __restrict__ ei, int E,
                                              uint32_t* __restrict__ pk,
                                              int* __restrict__ hist, int nblk, int NB) {
    __shared__ int lh[MAXNB];
    int base = blockIdx.x * CHUNK;
    int is64 = detect_is64(ei, base, E);
    for (int b = threadIdx.x; b < NB; b += 256) lh[b] = 0;
    __syncthreads();
    for (int j = threadIdx.x; j < CHUNK; j += 256) {
        int e = base + j;
        if (e < E) {
            int r = edge_at(ei, is64, e);
            int c = edge_at(ei, is64, (size_t)E + e);
            pk[e] = ((uint32_t)r << 16) | (uint32_t)c;
            atomicAdd(&lh[r >> SHB], 1);
        }
    }
    __syncthreads();
    for (int b = threadIdx.x; b < NB; b += 256)
        hist[(size_t)b * nblk + blockIdx.x] = lh[b];
}

__global__ void k_scanA(int* __restrict__ hist, int nblk, int* __restrict__ btot) {
    int b = blockIdx.x;
    int lane = threadIdx.x;
    int run = 0;
    for (int seg = 0; seg < nblk; seg += 64) {
        int idx = seg + lane;
        int v = (idx < nblk) ? hist[(size_t)b * nblk + idx] : 0;
        int s = v;
        for (int o = 1; o < 64; o <<= 1) {
            int t = __shfl_up(s, o);
            if (lane >= o) s += t;
        }
        if (idx < nblk) hist[(size_t)b * nblk + idx] = run + s - v;
        run += __shfl(s, 63);
    }
    if (lane == 0) btot[b] = run;
}

__global__ __launch_bounds__(256) void k_binwrite(const uint32_t* __restrict__ pk, int E,
                                                  const int* __restrict__ hist,
                                                  const int* __restrict__ btot,
                                                  uint32_t* __restrict__ ebuf,
                                                  int nblk, int NB) {
    __shared__ int s[MAXNB];
    __shared__ int lcnt[MAXNB];
    int t = threadIdx.x;
    for (int b = t; b < MAXNB; b += 256) s[b] = (b < NB) ? btot[b] : 0;
    __syncthreads();
    scan512(s);
    for (int b = t; b < NB; b += 256)
        lcnt[b] = s[b] - btot[b] + hist[(size_t)b * nblk + blockIdx.x];
    __syncthreads();
    int base = blockIdx.x * CHUNK;
    for (int j = t; j < CHUNK; j += 256) {
        int e = base + j;
        if (e < E) {
            uint32_t v = __builtin_nontemporal_load(&pk[e]);
            int pos = atomicAdd(&lcnt[v >> (16 + SHB)], 1);
            ebuf[pos] = v;
        }
    }
}

__global__ __launch_bounds__(256) void k_csr(const uint32_t* __restrict__ ebuf,
                                             const int* __restrict__ btot,
                                             int* __restrict__ rp, float* __restrict__ dinv,
                                             int* __restrict__ ecol, int N, int E, int NB) {
    __shared__ int s[MAXNB];
    __shared__ uint32_t seg[MAXSEG];
    __shared__ int cnt[NPB];
    __shared__ int sc[NPB];
    __shared__ int cur[NPB];
    int b = blockIdx.x;
    int tid = threadIdx.x;
    for (int k = tid; k < MAXNB; k += 256) s[k] = (k < NB) ? btot[k] : 0;
    __syncthreads();
    scan512(s);
    int p1 = s[b];
    int p0 = p1 - btot[b];
    int len = p1 - p0;
    bool fits = (len <= MAXSEG);
    int n0 = b << SHB;
    if (tid < NPB) cnt[tid] = 0;
    __syncthreads();
    if (fits) {
        for (int j = tid; j < len; j += 256) {
            uint32_t v = ebuf[p0 + j];
            seg[j] = v;
            atomicAdd(&cnt[(v >> 16) & (NPB - 1)], 1);
        }
    } else {
        for (int j = tid; j < len; j += 256)
            atomicAdd(&cnt[(ebuf[p0 + j] >> 16) & (NPB - 1)], 1);
    }
    __syncthreads();
    if (tid < NPB) sc[tid] = cnt[tid];
    __syncthreads();
    for (int o = 1; o < NPB; o <<= 1) {
        int v = (tid < NPB && tid >= o) ? sc[tid - o] : 0;
        __syncthreads();
        if (tid < NPB) sc[tid] += v;
        __syncthreads();
    }
    if (tid < NPB) {
        int off = sc[tid] - cnt[tid];
        cur[tid] = off;
        int node = n0 + tid;
        if (node < N) {
            rp[node] = p0 + off;
            int d = cnt[tid];
            dinv[node] = d > 0 ? rsqrtf((float)d) : 0.f;
        }
    }
    if (b == NB - 1 && tid == 0) rp[N] = E;
    __syncthreads();
    if (fits) {
        for (int j = tid; j < len; j += 256) {
            uint32_t v = seg[j];
            int pos = p0 + atomicAdd(&cur[(v >> 16) & (NPB - 1)], 1);
            ecol[pos] = (int)(v & 0xffffu);
        }
    } else {
        for (int j = tid; j < len; j += 256) {
            uint32_t v = ebuf[p0 + j];
            int pos = p0 + atomicAdd(&cur[(v >> 16) & (NPB - 1)], 1);
            ecol[pos] = (int)(v & 0xffffu);
        }
    }
}

// ---------------- GEMM1 (MFMA bf16) + fused layer-0 gate scalars + fp8 shadow ----------
__global__ __launch_bounds__(256) void k_gemm1(const float* __restrict__ A,
                                               const float* __restrict__ W,
                                               const float* __restrict__ bias,
                                               uint32_t* __restrict__ hb,
                                               uint32_t* __restrict__ hf,
                                               const float* __restrict__ gw0,
                                               const float* __restrict__ gb,
                                               const float* __restrict__ dinv,
                                               float* __restrict__ av,
                                               uint32_t* __restrict__ bdp, int M) {
    __shared__ char As[128 * 128];
    __shared__ char Bs[128 * 128];
    __shared__ float pab_a[2][128];
    __shared__ float pab_b[2][128];
    const int tid = threadIdx.x;
    const int lane = tid & 63;
    const int wave = tid >> 6;
    const int wr = wave >> 1, wc = wave & 1;
    const int m0 = blockIdx.x * 128;
    const int lrow = lane & 15, lkg = lane >> 4;
    const int sr = tid >> 3;
    const int sc = (tid & 7) * 8;

    f32x4 acc[4][4];
#pragma unroll
    for (int mi = 0; mi < 4; ++mi)
#pragma unroll
        for (int ni = 0; ni < 4; ++ni) acc[mi][ni] = (f32x4){0.f, 0.f, 0.f, 0.f};

    for (int t = 0; t < 4; ++t) {
        const int k0 = t * 64;
#pragma unroll
        for (int i = 0; i < 4; ++i) {
            int r = i * 32 + sr;
            float4 v0 = make_float4(0.f, 0.f, 0.f, 0.f), v1 = v0;
            if (m0 + r < M) {
                const float* p = &A[(size_t)(m0 + r) * 256 + k0 + sc];
                v0 = *(const float4*)p;
                v1 = *(const float4*)(p + 4);
            }
            uint4 pk = make_uint4(pack2(v0.x, v0.y), pack2(v0.z, v0.w),
                                  pack2(v1.x, v1.y), pack2(v1.z, v1.w));
            uint32_t off = (uint32_t)(r * 128 + sc * 2);
            *(uint4*)(As + (off ^ ((r & 7) << 4))) = pk;
        }
#pragma unroll
        for (int i = 0; i < 4; ++i) {
            int r = i * 32 + sr;
            const float* p = &W[(size_t)r * 256 + k0 + sc];
            float4 v0 = *(const float4*)p;
            float4 v1 = *(const float4*)(p + 4);
            uint4 pk = make_uint4(pack2(v0.x, v0.y), pack2(v0.z, v0.w),
                                  pack2(v1.x, v1.y), pack2(v1.z, v1.w));
            uint32_t off = (uint32_t)(r * 128 + sc * 2);
            *(uint4*)(Bs + (off ^ ((r & 7) << 4))) = pk;
        }
        __syncthreads();
#pragma unroll
        for (int ks = 0; ks < 2; ++ks) {
            bf16x8 af[4], bfr[4];
#pragma unroll
            for (int mi = 0; mi < 4; ++mi) {
                int r = wr * 64 + mi * 16 + lrow;
                uint32_t off = (uint32_t)(r * 128 + ks * 64 + lkg * 16);
                af[mi] = *(const bf16x8*)(As + (off ^ ((r & 7) << 4)));
            }
#pragma unroll
            for (int ni = 0; ni < 4; ++ni) {
                int r = wc * 64 + ni * 16 + lrow;
                uint32_t off = (uint32_t)(r * 128 + ks * 64 + lkg * 16);
                bfr[ni] = *(const bf16x8*)(Bs + (off ^ ((r & 7) << 4)));
            }
#pragma unroll
            for (int mi = 0; mi < 4; ++mi)
#pragma unroll
                for (int ni = 0; ni < 4; ++ni)
                    acc[mi][ni] = __builtin_amdgcn_mfma_f32_16x16x32_bf16(
                        af[mi], bfr[ni], acc[mi][ni], 0, 0, 0);
        }
        __syncthreads();
    }
    float bv[4], gi[4], gj[4];
#pragma unroll
    for (int ni = 0; ni < 4; ++ni) {
        int n = wc * 64 + ni * 16 + lrow;
        bv[ni] = bias[n];
        gi[ni] = gw0[n];
        gj[ni] = gw0[128 + n];
    }
#pragma unroll
    for (int mi = 0; mi < 4; ++mi) {
#pragma unroll
        for (int q = 0; q < 4; ++q) {
            float pa = 0.f, pb = 0.f;
            int m = m0 + wr * 64 + mi * 16 + lkg * 4 + q;
#pragma unroll
            for (int ni = 0; ni < 4; ++ni) {
                int n = wc * 64 + ni * 16 + lrow;
                float v = fmaxf(acc[mi][ni][q] + bv[ni], 0.f);
                float vp = __shfl_xor(v, 1);
                uint32_t lo = __builtin_amdgcn_cvt_pk_fp8_f32(v, vp, 0u, false);
                uint32_t hi2 = __shfl_xor(lo, 2);
                if (m < M) {
                    if (!(lane & 1)) hb[(size_t)m * 64 + (n >> 1)] = pack2(v, vp);
                    if (!(lane & 3)) hf[(size_t)m * 32 + (n >> 2)] = lo | (hi2 << 16);
                }
                pa = fmaf(v, gi[ni], pa);
                pb = fmaf(v, gj[ni], pb);
            }
#pragma unroll
            for (int o = 1; o < 16; o <<= 1) {
                pa += __shfl_xor(pa, o);
                pb += __shfl_xor(pb, o);
            }
            if (lrow == 0) {
                int rl = wr * 64 + mi * 16 + lkg * 4 + q;
                pab_a[wc][rl] = pa;
                pab_b[wc][rl] = pb;
            }
        }
    }
    __syncthreads();
    if (tid < 128) {
        int m = m0 + tid;
        if (m < M) {
            av[m] = pab_a[0][tid] + pab_a[1][tid] + gb[0];
            bdp[m] = pack2(pab_b[0][tid] + pab_b[1][tid], dinv[m]);
        }
    }
}

// ---------------- GEMM2 (MFMA bf16) + fused log_softmax ----------------
__global__ __launch_bounds__(256) void k_gemm2(const uint32_t* __restrict__ Abf,
                                               const float* __restrict__ W,
                                               const float* __restrict__ bias,
                                               float* __restrict__ out, int M) {
    __shared__ char As[128 * 128];
    __shared__ char Bs[64 * 128];
    __shared__ float redmax[2][128];
    __shared__ float redsum[2][128];
    const int tid = threadIdx.x;
    const int lane = tid & 63;
    const int wave = tid >> 6;
    const int wr = wave >> 1, wc = wave & 1;
    const int m0 = blockIdx.x * 128;
    const int lrow = lane & 15, lkg = lane >> 4;

    f32x4 acc[4][2];
#pragma unroll
    for (int mi = 0; mi < 4; ++mi)
#pragma unroll
        for (int ni = 0; ni < 2; ++ni) acc[mi][ni] = (f32x4){0.f, 0.f, 0.f, 0.f};

    for (int t = 0; t < 2; ++t) {
#pragma unroll
        for (int i = 0; i < 4; ++i) {
            int r = i * 32 + (tid >> 3);
            uint4 v = make_uint4(0u, 0u, 0u, 0u);
            if (m0 + r < M)
                v = *(const uint4*)&Abf[(size_t)(m0 + r) * 64 + t * 32 + (tid & 7) * 4];
            uint32_t off = (uint32_t)(r * 128 + (tid & 7) * 16);
            *(uint4*)(As + (off ^ ((r & 7) << 4))) = v;
        }
#pragma unroll
        for (int i = 0; i < 2; ++i) {
            int r = i * 32 + (tid >> 3);
            const float* p = &W[(size_t)r * 128 + t * 64 + (tid & 7) * 8];
            float4 v0 = *(const float4*)p, v1 = *(const float4*)(p + 4);
            uint4 pk = make_uint4(pack2(v0.x, v0.y), pack2(v0.z, v0.w),
                                  pack2(v1.x, v1.y), pack2(v1.z, v1.w));
            uint32_t off = (uint32_t)(r * 128 + (tid & 7) * 16);
            *(uint4*)(Bs + (off ^ ((r & 7) << 4))) = pk;
        }
        __syncthreads();
#pragma unroll
        for (int ks = 0; ks < 2; ++ks) {
            bf16x8 af[4], bfr[2];
#pragma unroll
            for (int mi = 0; mi < 4; ++mi) {
                int r = wr * 64 + mi * 16 + lrow;
                uint32_t off = (uint32_t)(r * 128 + ks * 64 + lkg * 16);
                af[mi] = *(const bf16x8*)(As + (off ^ ((r & 7) << 4)));
            }
#pragma unroll
            for (int ni = 0; ni < 2; ++ni) {
                int r = wc * 32 + ni * 16 + lrow;
                uint32_t off = (uint32_t)(r * 128 + ks * 64 + lkg * 16);
                bfr[ni] = *(const bf16x8*)(Bs + (off ^ ((r & 7) << 4)));
            }
#pragma unroll
            for (int mi = 0; mi < 4; ++mi)
#pragma unroll
                for (int ni = 0; ni < 2; ++ni)
                    acc[mi][ni] = __builtin_amdgcn_mfma_f32_16x16x32_bf16(
                        af[mi], bfr[ni], acc[mi][ni], 0, 0, 0);
        }
        __syncthreads();
    }

    float vb[4][2][4];
#pragma unroll
    for (int mi = 0; mi < 4; ++mi)
#pragma unroll
        for (int ni = 0; ni < 2; ++ni) {
            float bvx = bias[wc * 32 + ni * 16 + lrow];
#pragma unroll
            for (int q = 0; q < 4; ++q) vb[mi][ni][q] = acc[mi][ni][q] + bvx;
        }
#pragma unroll
    for (int mi = 0; mi < 4; ++mi)
#pragma unroll
        for (int q = 0; q < 4; ++q) {
            float mx = fmaxf(vb[mi][0][q], vb[mi][1][q]);
#pragma unroll
            for (int o = 1; o < 16; o <<= 1) mx = fmaxf(mx, __shfl_xor(mx, o));
            if (lrow == 0) redmax[wc][wr * 64 + mi * 16 + lkg * 4 + q] = mx;
        }
    __syncthreads();
    float fmv[4][4];
#pragma unroll
    for (int mi = 0; mi < 4; ++mi)
#pragma unroll
        for (int q = 0; q < 4; ++q) {
            int rl = wr * 64 + mi * 16 + lkg * 4 + q;
            float fm = fmaxf(redmax[0][rl], redmax[1][rl]);
            fmv[mi][q] = fm;
            float e = expf(vb[mi][0][q] - fm) + expf(vb[mi][1][q] - fm);
#pragma unroll
            for (int o = 1; o < 16; o <<= 1) e += __shfl_xor(e, o);
            if (lrow == 0) redsum[wc][rl] = e;
        }
    __syncthreads();
#pragma unroll
    for (int mi = 0; mi < 4; ++mi)
#pragma unroll
        for (int q = 0; q < 4; ++q) {
            int rl = wr * 64 + mi * 16 + lkg * 4 + q;
            int m = m0 + rl;
            if (m < M) {
                float ls = logf(redsum[0][rl] + redsum[1][rl]) + fmv[mi][q];
                out[(size_t)m * 64 + wc * 32 + lrow] = vb[mi][0][q] - ls;
                out[(size_t)m * 64 + wc * 32 + 16 + lrow] = vb[mi][1][q] - ls;
            }
        }
}

// ---------------- aggregation (R15 shape + full-batch MLP) ----------------
// 16 lanes/edge x uint2; per batch: issue ALL bpermutes, then ALL gathers
// (max 16 in flight), then all FMAs. Static 4-window unroll, wave-uniform guards.
template <bool FUSE_AB, bool RAW_NT>
__global__ __launch_bounds__(256) void k_agg(const uint32_t* __restrict__ hf,
                                             const uint32_t* __restrict__ raw,
                                             const int* __restrict__ rp,
                                             const int* __restrict__ ecol,
                                             const float* __restrict__ av,
                                             const uint32_t* __restrict__ bdp,
                                             const float* __restrict__ dinv,
                                             uint32_t* __restrict__ hb_out,
                                             uint32_t* __restrict__ hf_out,
                                             const float* __restrict__ gw_next,
                                             const float* __restrict__ gb_next,
                                             float* __restrict__ av_out,
                                             uint32_t* __restrict__ bdp_out, int N) {
    int wid = threadIdx.x >> 6, lane = threadIdx.x & 63;
    int i = blockIdx.x * 4 + wid;
    if (i >= N) return;
    int iu = __builtin_amdgcn_readfirstlane(i);
    int p0 = __builtin_amdgcn_readfirstlane(rp[iu]);
    int p1 = __builtin_amdgcn_readfirstlane(rp[iu + 1]);
    float a_i = av[iu];
    float di = dinv[iu];
    const int lg = lane >> 4;   // edge sub-slot (4)
    const int ll = lane & 15;   // channel octet (16 x 8 ch)
    const char* hfp = (const char*)hf + (ll << 3);  // per-lane gather base (8B)

    // issue raw-row load EARLY so its latency hides under the gather loop
    uint32_t r0 = 0, r1 = 0, r2 = 0, r3 = 0;
    if (lane < 16) {
        const uint32_t* rpt = raw + (size_t)i * 64 + ll * 4;
        if (RAW_NT) {
            r0 = __builtin_nontemporal_load(rpt + 0);
            r1 = __builtin_nontemporal_load(rpt + 1);
            r2 = __builtin_nontemporal_load(rpt + 2);
            r3 = __builtin_nontemporal_load(rpt + 3);
        } else {
            r0 = rpt[0]; r1 = rpt[1]; r2 = rpt[2]; r3 = rpt[3];
        }
    }

    float acc[8];
#pragma unroll
    for (int j = 0; j < 8; ++j) acc[j] = 0.f;

#define FMA8F8(W, U)                                                   \
    {                                                                  \
        auto p01 = __builtin_amdgcn_cvt_pk_f32_fp8((U).x, false);      \
        auto p23 = __builtin_amdgcn_cvt_pk_f32_fp8((U).x, true);       \
        auto p45 = __builtin_amdgcn_cvt_pk_f32_fp8((U).y, false);      \
        auto p67 = __builtin_amdgcn_cvt_pk_f32_fp8((U).y, true);       \
        acc[0] = fmaf(W, p01[0], acc[0]); acc[1] = fmaf(W, p01[1], acc[1]); \
        acc[2] = fmaf(W, p23[0], acc[2]); acc[3] = fmaf(W, p23[1], acc[3]); \
        acc[4] = fmaf(W, p45[0], acc[4]); acc[5] = fmaf(W, p45[1], acc[5]); \
        acc[6] = fmaf(W, p67[0], acc[6]); acc[7] = fmaf(W, p67[1], acc[7]); \
    }

    for (int b0 = p0; b0 < p1; b0 += 64) {
        int cnt = min(64, p1 - b0);
        // Phase A: weights for this batch (pad lanes: w=0, c=0 -> L1-hot row 0)
        uint32_t wcp = 0u;
        if (lane < cnt) {
            int c = __builtin_nontemporal_load(&ecol[b0 + lane]);
            uint32_t t = bdp[c];
            float w = fast_tanh(a_i + bflo(t)) * bfhi(t);
            wcp = (f2bf(w) << 16) | (uint32_t)c;
        }
        // Phase B1: issue ALL bpermutes for the batch (static 4-window unroll)
        uint32_t wx[16];
        uint2 ug[16];
#pragma unroll
        for (int w = 0; w < 4; ++w) {
            if (w * 16 < cnt) {
                int kb = (w * 16 + lg) << 2;
                wx[w * 4 + 0] = __builtin_amdgcn_ds_bpermute(kb, (int)wcp);
                wx[w * 4 + 1] = __builtin_amdgcn_ds_bpermute(kb + 16, (int)wcp);
                wx[w * 4 + 2] = __builtin_amdgcn_ds_bpermute(kb + 32, (int)wcp);
                wx[w * 4 + 3] = __builtin_amdgcn_ds_bpermute(kb + 48, (int)wcp);
            }
        }
        // Phase B2: issue ALL gathers back-to-back (max 16 in flight)
#pragma unroll
        for (int w = 0; w < 4; ++w) {
            if (w * 16 < cnt) {
                ug[w * 4 + 0] = *(const uint2*)(hfp + ((wx[w * 4 + 0] & 0xffffu) << 7));
                ug[w * 4 + 1] = *(const uint2*)(hfp + ((wx[w * 4 + 1] & 0xffffu) << 7));
                ug[w * 4 + 2] = *(const uint2*)(hfp + ((wx[w * 4 + 2] & 0xffffu) << 7));
                ug[w * 4 + 3] = *(const uint2*)(hfp + ((wx[w * 4 + 3] & 0xffffu) << 7));
            }
        }
        // Phase B3: FMAs
#pragma unroll
        for (int w = 0; w < 4; ++w) {
            if (w * 16 < cnt) {
                FMA8F8(bfhi(wx[w * 4 + 0]), ug[w * 4 + 0]);
                FMA8F8(bfhi(wx[w * 4 + 1]), ug[w * 4 + 1]);
                FMA8F8(bfhi(wx[w * 4 + 2]), ug[w * 4 + 2]);
                FMA8F8(bfhi(wx[w * 4 + 3]), ug[w * 4 + 3]);
            }
        }
    }
#undef FMA8F8
    // reduce across the 4 edge sub-slots
#pragma unroll
    for (int j = 0; j < 8; ++j) {
        acc[j] += __shfl_xor(acc[j], 16);
        acc[j] += __shfl_xor(acc[j], 32);
    }
    // epilogue: lanes 0-15 own 8 channels each (ch = ll*8 + j)
    if (lane < 16) {
        float o[8];
        o[0] = EPSF * bflo(r0) + di * acc[0]; o[1] = EPSF * bfhi(r0) + di * acc[1];
        o[2] = EPSF * bflo(r1) + di * acc[2]; o[3] = EPSF * bfhi(r1) + di * acc[3];
        o[4] = EPSF * bflo(r2) + di * acc[4]; o[5] = EPSF * bfhi(r2) + di * acc[5];
        o[6] = EPSF * bflo(r3) + di * acc[6]; o[7] = EPSF * bfhi(r3) + di * acc[7];
        uint4 w4;
        w4.x = pack2(o[0], o[1]); w4.y = pack2(o[2], o[3]);
        w4.z = pack2(o[4], o[5]); w4.w = pack2(o[6], o[7]);
        *((uint4*)(hb_out + (size_t)i * 64) + ll) = w4;
        if (FUSE_AB) {
            // fp8 shadow for next layer's gather
            uint32_t pk8a = 0, pk8b = 0;
            pk8a = __builtin_amdgcn_cvt_pk_fp8_f32(o[0], o[1], pk8a, false);
            pk8a = __builtin_amdgcn_cvt_pk_fp8_f32(o[2], o[3], pk8a, true);
            pk8b = __builtin_amdgcn_cvt_pk_fp8_f32(o[4], o[5], pk8b, false);
            pk8b = __builtin_amdgcn_cvt_pk_fp8_f32(o[6], o[7], pk8b, true);
            *((uint2*)(hf_out + (size_t)i * 32) + ll) = make_uint2(pk8a, pk8b);
            // next-layer gate scalars
            float pa = 0.f, pb = 0.f;
#pragma unroll
            for (int j = 0; j < 8; ++j) {
                int ch = ll * 8 + j;
                pa = fmaf(o[j], gw_next[ch], pa);
                pb = fmaf(o[j], gw_next[128 + ch], pb);
            }
#pragma unroll
            for (int off = 1; off < 16; off <<= 1) {
                pa += __shfl_xor(pa, off);
                pb += __shfl_xor(pb, off);
            }
            if (ll == 0) {
                av_out[i] = pa + gb_next[0];
                bdp_out[i] = pack2(pb, di);
            }
        }
    }
}

extern "C" void kernel_launch(void* const* d_in, const int* in_sizes, int n_in,
                              void* d_out, int out_size, void* d_ws, size_t ws_size,
                              hipStream_t stream) {
    const float* x = (const float*)d_in[0];
    const int* ei = (const int*)d_in[1];
    const float* t1w = (const float*)d_in[2];
    const float* t1b = (const float*)d_in[3];
    const float* gw = (const float*)d_in[4];
    const float* gb = (const float*)d_in[5];
    const float* t2w = (const float*)d_in[6];
    const float* t2b = (const float*)d_in[7];
    float* out = (float*)d_out;

    const int INC = 256;
    const int N = in_sizes[0] / INC;
    const int E = in_sizes[1] / 2;
    const int NB = (N + NPB - 1) >> SHB;
    const int nblk = (E + CHUNK - 1) / CHUNK;
    const int nbb = (N + 3) / 4;

    char* ws = (char*)d_ws;
    auto alloc = [&](size_t bytes) {
        char* p = ws;
        ws += (bytes + 255) & ~(size_t)255;
        return p;
    };
    uint32_t* pk = (uint32_t*)alloc((size_t)E * 4);
    int* hist = (int*)alloc((size_t)NB * nblk * 4);
    int* btot = (int*)alloc((size_t)NB * 4);
    uint32_t* ebuf = (uint32_t*)alloc((size_t)E * 4);
    int* rp = (int*)alloc((size_t)(N + 1) * 4);
    float* dinv = (float*)alloc((size_t)N * 4);
    int* ecol = (int*)alloc((size_t)E * 4);
    float* av0 = (float*)alloc((size_t)N * 4);
    float* av1 = (float*)alloc((size_t)N * 4);
    uint32_t* bdp0 = (uint32_t*)alloc((size_t)N * 4);
    uint32_t* bdp1 = (uint32_t*)alloc((size_t)N * 4);
    uint32_t* hb0 = (uint32_t*)alloc((size_t)N * 64 * 4);
    uint32_t* hb1 = (uint32_t*)alloc((size_t)N * 64 * 4);
    uint32_t* hb2 = (uint32_t*)alloc((size_t)N * 64 * 4);
    uint32_t* hf0 = (uint32_t*)alloc((size_t)N * 32 * 4);
    uint32_t* hf1 = (uint32_t*)alloc((size_t)N * 32 * 4);

    // ---- CSR build ----
    k_pack<<<nblk, 256, 0, stream>>>(ei, E, pk, hist, nblk, NB);
    k_scanA<<<NB, 64, 0, stream>>>(hist, nblk, btot);
    k_binwrite<<<nblk, 256, 0, stream>>>(pk, E, hist, btot, ebuf, nblk, NB);
    k_csr<<<NB, 256, 0, stream>>>(ebuf, btot, rp, dinv, ecol, N, E, NB);

    // ---- hb0/hf0 = relu(x @ t1_w^T + t1_b) + layer-0 gate scalars ----
    k_gemm1<<<(N + 127) / 128, 256, 0, stream>>>(x, t1w, t1b, hb0, hf0,
                                                 gw + 0 * 256, gb, dinv, av0, bdp0, N);

    // ---- layer 0: gather hf0 -> hb1 + hf1, fused layer-1 gate scalars ----
    k_agg<true, false><<<nbb, 256, 0, stream>>>(
        hf0, hb0, rp, ecol, av0, bdp0, dinv, hb1, hf1,
        gw + 1 * 256, gb + 1, av1, bdp1, N);
    // ---- layer 1: gather hf1 -> hb2 (raw = hb0, nontemporal) ----
    k_agg<false, true><<<nbb, 256, 0, stream>>>(
        hf1, hb0, rp, ecol, av1, bdp1, dinv, hb2, nullptr,
        nullptr, nullptr, nullptr, nullptr, N);

    // ---- out = log_softmax(hb2 @ t2_w^T + t2_b) ----
    k_gemm2<<<(N + 127) / 128, 256, 0, stream>>>(hb2, t2w, t2b, out, N);
}

// Round 17
// 164.094 us; speedup vs baseline: 1.1855x; 1.1855x over previous
//
#include <hip/hip_runtime.h>
#include <math.h>

#define EPSF 0.3f
#define NPB 128      // nodes per row-bucket
#define SHB 7        // log2(NPB)
#define MAXNB 512    // max buckets (N <= 65536; packed-edge limit N < 65536)
#define CHUNK 4096   // edges per block in pack/binwrite
#define MAXSEG 8192  // LDS-staged edges per bucket in k_csr (avg ~4090)

typedef __attribute__((ext_vector_type(8))) short bf16x8;
typedef __attribute__((ext_vector_type(4))) float f32x4;

// ---------------- bf16 helpers ----------------
__device__ __forceinline__ uint32_t f2bf(float f) {
    uint32_t u = __float_as_uint(f);
    return (u + 0x7fffu + ((u >> 16) & 1u)) >> 16;  // RNE
}
__device__ __forceinline__ uint32_t pack2(float lo, float hi) {
    return f2bf(lo) | (f2bf(hi) << 16);
}
__device__ __forceinline__ float bflo(uint32_t u) { return __uint_as_float(u << 16); }
__device__ __forceinline__ float bfhi(uint32_t u) { return __uint_as_float(u & 0xffff0000u); }

// fast tanh: 1 - 2/(e^{2x}+1)
__device__ __forceinline__ float fast_tanh(float x) {
    float e = __expf(2.f * x);
    return 1.f - 2.f * __builtin_amdgcn_rcpf(e + 1.f);
}

__device__ __forceinline__ int edge_at(const int* ei, int is64, size_t idx) {
    if (is64) return (int)((const long long*)ei)[idx];
    return ei[idx];
}

__device__ __forceinline__ int detect_is64(const int* ei, int base, int E) {
    __shared__ int s_nz;
    if (threadIdx.x == 0) s_nz = 0;
    __syncthreads();
    int lim = min(512, E - base);
    int nz = 0;
    for (int t = threadIdx.x; t < lim; t += 256)
        nz |= (ei[2 * (size_t)(base + t) + 1] != 0);
    if (nz) atomicOr(&s_nz, 1);
    __syncthreads();
    return s_nz == 0;
}

// 512-entry inclusive scan in LDS (256 threads, 2 slots each)
__device__ __forceinline__ void scan512(int* s) {
    int t = threadIdx.x;
    for (int o = 1; o < MAXNB; o <<= 1) {
        int i2 = t + 256;
        int x1 = (t >= o) ? s[t - o] : 0;
        int x2 = (i2 >= o) ? s[i2 - o] : 0;
        __syncthreads();
        s[t] += x1;
        s[i2] += x2;
        __syncthreads();
    }
}

// ---------------- pack + bucket histogram ----------------
__global__ __launch_bounds__(256) void k_pack(const int* __restrict__ ei, int E,
                                              uint32_t* __restrict__ pk,
                                              int* __restrict__ hist, int nblk, int NB) {
    __shared__ int lh[MAXNB];
    int base = blockIdx.x * CHUNK;
    int is64 = detect_is64(ei, base, E);
    for (int b = threadIdx.x; b < NB; b += 256) lh[b] = 0;
    __syncthreads();
    for (int j = threadIdx.x; j < CHUNK; j += 256) {
        int e = base + j;
        if (e < E) {
            int r = edge_at(ei, is64, e);
            int c = edge_at(ei, is64, (size_t)E + e);
            pk[e] = ((uint32_t)r << 16) | (uint32_t)c;
            atomicAdd(&lh[r >> SHB], 1);
        }
    }
    __syncthreads();
    for (int b = threadIdx.x; b < NB; b += 256)
        hist[(size_t)b * nblk + blockIdx.x] = lh[b];
}

__global__ void k_scanA(int* __restrict__ hist, int nblk, int* __restrict__ btot) {
    int b = blockIdx.x;
    int lane = threadIdx.x;
    int run = 0;
    for (int seg = 0; seg < nblk; seg += 64) {
        int idx = seg + lane;
        int v = (idx < nblk) ? hist[(size_t)b * nblk + idx] : 0;
        int s = v;
        for (int o = 1; o < 64; o <<= 1) {
            int t = __shfl_up(s, o);
            if (lane >= o) s += t;
        }
        if (idx < nblk) hist[(size_t)b * nblk + idx] = run + s - v;
        run += __shfl(s, 63);
    }
    if (lane == 0) btot[b] = run;
}

__global__ __launch_bounds__(256) void k_binwrite(const uint32_t* __restrict__ pk, int E,
                                                  const int* __restrict__ hist,
                                                  const int* __restrict__ btot,
                                                  uint32_t* __restrict__ ebuf,
                                                  int nblk, int NB) {
    __shared__ int s[MAXNB];
    __shared__ int lcnt[MAXNB];
    int t = threadIdx.x;
    for (int b = t; b < MAXNB; b += 256) s[b] = (b < NB) ? btot[b] : 0;
    __syncthreads();
    scan512(s);
    for (int b = t; b < NB; b += 256)
        lcnt[b] = s[b] - btot[b] + hist[(size_t)b * nblk + blockIdx.x];
    __syncthreads();
    int base = blockIdx.x * CHUNK;
    for (int j = t; j < CHUNK; j += 256) {
        int e = base + j;
        if (e < E) {
            uint32_t v = __builtin_nontemporal_load(&pk[e]);
            int pos = atomicAdd(&lcnt[v >> (16 + SHB)], 1);
            ebuf[pos] = v;
        }
    }
}

__global__ __launch_bounds__(256) void k_csr(const uint32_t* __restrict__ ebuf,
                                             const int* __restrict__ btot,
                                             int* __restrict__ rp, float* __restrict__ dinv,
                                             int* __restrict__ ecol, int N, int E, int NB) {
    __shared__ int s[MAXNB];
    __shared__ uint32_t seg[MAXSEG];
    __shared__ int cnt[NPB];
    __shared__ int sc[NPB];
    __shared__ int cur[NPB];
    int b = blockIdx.x;
    int tid = threadIdx.x;
    for (int k = tid; k < MAXNB; k += 256) s[k] = (k < NB) ? btot[k] : 0;
    __syncthreads();
    scan512(s);
    int p1 = s[b];
    int p0 = p1 - btot[b];
    int len = p1 - p0;
    bool fits = (len <= MAXSEG);
    int n0 = b << SHB;
    if (tid < NPB) cnt[tid] = 0;
    __syncthreads();
    if (fits) {
        for (int j = tid; j < len; j += 256) {
            uint32_t v = ebuf[p0 + j];
            seg[j] = v;
            atomicAdd(&cnt[(v >> 16) & (NPB - 1)], 1);
        }
    } else {
        for (int j = tid; j < len; j += 256)
            atomicAdd(&cnt[(ebuf[p0 + j] >> 16) & (NPB - 1)], 1);
    }
    __syncthreads();
    if (tid < NPB) sc[tid] = cnt[tid];
    __syncthreads();
    for (int o = 1; o < NPB; o <<= 1) {
        int v = (tid < NPB && tid >= o) ? sc[tid - o] : 0;
        __syncthreads();
        if (tid < NPB) sc[tid] += v;
        __syncthreads();
    }
    if (tid < NPB) {
        int off = sc[tid] - cnt[tid];
        cur[tid] = off;
        int node = n0 + tid;
        if (node < N) {
            rp[node] = p0 + off;
            int d = cnt[tid];
            dinv[node] = d > 0 ? rsqrtf((float)d) : 0.f;
        }
    }
    if (b == NB - 1 && tid == 0) rp[N] = E;
    __syncthreads();
    if (fits) {
        for (int j = tid; j < len; j += 256) {
            uint32_t v = seg[j];
            int pos = p0 + atomicAdd(&cur[(v >> 16) & (NPB - 1)], 1);
            ecol[pos] = (int)(v & 0xffffu);
        }
    } else {
        for (int j = tid; j < len; j += 256) {
            uint32_t v = ebuf[p0 + j];
            int pos = p0 + atomicAdd(&cur[(v >> 16) & (NPB - 1)], 1);
            ecol[pos] = (int)(v & 0xffffu);
        }
    }
}

// ---------------- GEMM1 (MFMA bf16) + fused layer-0 gate scalars + fp8 shadow ----------
__global__ __launch_bounds__(256) void k_gemm1(const float* __restrict__ A,
                                               const float* __restrict__ W,
                                               const float* __restrict__ bias,
                                               uint32_t* __restrict__ hb,
                                               uint32_t* __restrict__ hf,
                                               const float* __restrict__ gw0,
                                               const float* __restrict__ gb,
                                               const float* __restrict__ dinv,
                                               float* __restrict__ av,
                                               uint32_t* __restrict__ bdp, int M) {
    __shared__ char As[128 * 128];
    __shared__ char Bs[128 * 128];
    __shared__ float pab_a[2][128];
    __shared__ float pab_b[2][128];
    const int tid = threadIdx.x;
    const int lane = tid & 63;
    const int wave = tid >> 6;
    const int wr = wave >> 1, wc = wave & 1;
    const int m0 = blockIdx.x * 128;
    const int lrow = lane & 15, lkg = lane >> 4;
    const int sr = tid >> 3;
    const int sc = (tid & 7) * 8;

    f32x4 acc[4][4];
#pragma unroll
    for (int mi = 0; mi < 4; ++mi)
#pragma unroll
        for (int ni = 0; ni < 4; ++ni) acc[mi][ni] = (f32x4){0.f, 0.f, 0.f, 0.f};

    for (int t = 0; t < 4; ++t) {
        const int k0 = t * 64;
#pragma unroll
        for (int i = 0; i < 4; ++i) {
            int r = i * 32 + sr;
            float4 v0 = make_float4(0.f, 0.f, 0.f, 0.f), v1 = v0;
            if (m0 + r < M) {
                const float* p = &A[(size_t)(m0 + r) * 256 + k0 + sc];
                v0 = *(const float4*)p;
                v1 = *(const float4*)(p + 4);
            }
            uint4 pk = make_uint4(pack2(v0.x, v0.y), pack2(v0.z, v0.w),
                                  pack2(v1.x, v1.y), pack2(v1.z, v1.w));
            uint32_t off = (uint32_t)(r * 128 + sc * 2);
            *(uint4*)(As + (off ^ ((r & 7) << 4))) = pk;
        }
#pragma unroll
        for (int i = 0; i < 4; ++i) {
            int r = i * 32 + sr;
            const float* p = &W[(size_t)r * 256 + k0 + sc];
            float4 v0 = *(const float4*)p;
            float4 v1 = *(const float4*)(p + 4);
            uint4 pk = make_uint4(pack2(v0.x, v0.y), pack2(v0.z, v0.w),
                                  pack2(v1.x, v1.y), pack2(v1.z, v1.w));
            uint32_t off = (uint32_t)(r * 128 + sc * 2);
            *(uint4*)(Bs + (off ^ ((r & 7) << 4))) = pk;
        }
        __syncthreads();
#pragma unroll
        for (int ks = 0; ks < 2; ++ks) {
            bf16x8 af[4], bfr[4];
#pragma unroll
            for (int mi = 0; mi < 4; ++mi) {
                int r = wr * 64 + mi * 16 + lrow;
                uint32_t off = (uint32_t)(r * 128 + ks * 64 + lkg * 16);
                af[mi] = *(const bf16x8*)(As + (off ^ ((r & 7) << 4)));
            }
#pragma unroll
            for (int ni = 0; ni < 4; ++ni) {
                int r = wc * 64 + ni * 16 + lrow;
                uint32_t off = (uint32_t)(r * 128 + ks * 64 + lkg * 16);
                bfr[ni] = *(const bf16x8*)(Bs + (off ^ ((r & 7) << 4)));
            }
#pragma unroll
            for (int mi = 0; mi < 4; ++mi)
#pragma unroll
                for (int ni = 0; ni < 4; ++ni)
                    acc[mi][ni] = __builtin_amdgcn_mfma_f32_16x16x32_bf16(
                        af[mi], bfr[ni], acc[mi][ni], 0, 0, 0);
        }
        __syncthreads();
    }
    float bv[4], gi[4], gj[4];
#pragma unroll
    for (int ni = 0; ni < 4; ++ni) {
        int n = wc * 64 + ni * 16 + lrow;
        bv[ni] = bias[n];
        gi[ni] = gw0[n];
        gj[ni] = gw0[128 + n];
    }
#pragma unroll
    for (int mi = 0; mi < 4; ++mi) {
#pragma unroll
        for (int q = 0; q < 4; ++q) {
            float pa = 0.f, pb = 0.f;
            int m = m0 + wr * 64 + mi * 16 + lkg * 4 + q;
#pragma unroll
            for (int ni = 0; ni < 4; ++ni) {
                int n = wc * 64 + ni * 16 + lrow;
                float v = fmaxf(acc[mi][ni][q] + bv[ni], 0.f);
                float vp = __shfl_xor(v, 1);
                uint32_t lo = __builtin_amdgcn_cvt_pk_fp8_f32(v, vp, 0u, false);
                uint32_t hi2 = __shfl_xor(lo, 2);
                if (m < M) {
                    if (!(lane & 1)) hb[(size_t)m * 64 + (n >> 1)] = pack2(v, vp);
                    if (!(lane & 3)) hf[(size_t)m * 32 + (n >> 2)] = lo | (hi2 << 16);
                }
                pa = fmaf(v, gi[ni], pa);
                pb = fmaf(v, gj[ni], pb);
            }
#pragma unroll
            for (int o = 1; o < 16; o <<= 1) {
                pa += __shfl_xor(pa, o);
                pb += __shfl_xor(pb, o);
            }
            if (lrow == 0) {
                int rl = wr * 64 + mi * 16 + lkg * 4 + q;
                pab_a[wc][rl] = pa;
                pab_b[wc][rl] = pb;
            }
        }
    }
    __syncthreads();
    if (tid < 128) {
        int m = m0 + tid;
        if (m < M) {
            av[m] = pab_a[0][tid] + pab_a[1][tid] + gb[0];
            bdp[m] = pack2(pab_b[0][tid] + pab_b[1][tid], dinv[m]);
        }
    }
}

// ---------------- GEMM2 (MFMA bf16) + fused log_softmax ----------------
__global__ __launch_bounds__(256) void k_gemm2(const uint32_t* __restrict__ Abf,
                                               const float* __restrict__ W,
                                               const float* __restrict__ bias,
                                               float* __restrict__ out, int M) {
    __shared__ char As[128 * 128];
    __shared__ char Bs[64 * 128];
    __shared__ float redmax[2][128];
    __shared__ float redsum[2][128];
    const int tid = threadIdx.x;
    const int lane = tid & 63;
    const int wave = tid >> 6;
    const int wr = wave >> 1, wc = wave & 1;
    const int m0 = blockIdx.x * 128;
    const int lrow = lane & 15, lkg = lane >> 4;

    f32x4 acc[4][2];
#pragma unroll
    for (int mi = 0; mi < 4; ++mi)
#pragma unroll
        for (int ni = 0; ni < 2; ++ni) acc[mi][ni] = (f32x4){0.f, 0.f, 0.f, 0.f};

    for (int t = 0; t < 2; ++t) {
#pragma unroll
        for (int i = 0; i < 4; ++i) {
            int r = i * 32 + (tid >> 3);
            uint4 v = make_uint4(0u, 0u, 0u, 0u);
            if (m0 + r < M)
                v = *(const uint4*)&Abf[(size_t)(m0 + r) * 64 + t * 32 + (tid & 7) * 4];
            uint32_t off = (uint32_t)(r * 128 + (tid & 7) * 16);
            *(uint4*)(As + (off ^ ((r & 7) << 4))) = v;
        }
#pragma unroll
        for (int i = 0; i < 2; ++i) {
            int r = i * 32 + (tid >> 3);
            const float* p = &W[(size_t)r * 128 + t * 64 + (tid & 7) * 8];
            float4 v0 = *(const float4*)p, v1 = *(const float4*)(p + 4);
            uint4 pk = make_uint4(pack2(v0.x, v0.y), pack2(v0.z, v0.w),
                                  pack2(v1.x, v1.y), pack2(v1.z, v1.w));
            uint32_t off = (uint32_t)(r * 128 + (tid & 7) * 16);
            *(uint4*)(Bs + (off ^ ((r & 7) << 4))) = pk;
        }
        __syncthreads();
#pragma unroll
        for (int ks = 0; ks < 2; ++ks) {
            bf16x8 af[4], bfr[2];
#pragma unroll
            for (int mi = 0; mi < 4; ++mi) {
                int r = wr * 64 + mi * 16 + lrow;
                uint32_t off = (uint32_t)(r * 128 + ks * 64 + lkg * 16);
                af[mi] = *(const bf16x8*)(As + (off ^ ((r & 7) << 4)));
            }
#pragma unroll
            for (int ni = 0; ni < 2; ++ni) {
                int r = wc * 32 + ni * 16 + lrow;
                uint32_t off = (uint32_t)(r * 128 + ks * 64 + lkg * 16);
                bfr[ni] = *(const bf16x8*)(Bs + (off ^ ((r & 7) << 4)));
            }
#pragma unroll
            for (int mi = 0; mi < 4; ++mi)
#pragma unroll
                for (int ni = 0; ni < 2; ++ni)
                    acc[mi][ni] = __builtin_amdgcn_mfma_f32_16x16x32_bf16(
                        af[mi], bfr[ni], acc[mi][ni], 0, 0, 0);
        }
        __syncthreads();
    }

    float vb[4][2][4];
#pragma unroll
    for (int mi = 0; mi < 4; ++mi)
#pragma unroll
        for (int ni = 0; ni < 2; ++ni) {
            float bvx = bias[wc * 32 + ni * 16 + lrow];
#pragma unroll
            for (int q = 0; q < 4; ++q) vb[mi][ni][q] = acc[mi][ni][q] + bvx;
        }
#pragma unroll
    for (int mi = 0; mi < 4; ++mi)
#pragma unroll
        for (int q = 0; q < 4; ++q) {
            float mx = fmaxf(vb[mi][0][q], vb[mi][1][q]);
#pragma unroll
            for (int o = 1; o < 16; o <<= 1) mx = fmaxf(mx, __shfl_xor(mx, o));
            if (lrow == 0) redmax[wc][wr * 64 + mi * 16 + lkg * 4 + q] = mx;
        }
    __syncthreads();
    float fmv[4][4];
#pragma unroll
    for (int mi = 0; mi < 4; ++mi)
#pragma unroll
        for (int q = 0; q < 4; ++q) {
            int rl = wr * 64 + mi * 16 + lkg * 4 + q;
            float fm = fmaxf(redmax[0][rl], redmax[1][rl]);
            fmv[mi][q] = fm;
            float e = expf(vb[mi][0][q] - fm) + expf(vb[mi][1][q] - fm);
#pragma unroll
            for (int o = 1; o < 16; o <<= 1) e += __shfl_xor(e, o);
            if (lrow == 0) redsum[wc][rl] = e;
        }
    __syncthreads();
#pragma unroll
    for (int mi = 0; mi < 4; ++mi)
#pragma unroll
        for (int q = 0; q < 4; ++q) {
            int rl = wr * 64 + mi * 16 + lkg * 4 + q;
            int m = m0 + rl;
            if (m < M) {
                float ls = logf(redsum[0][rl] + redsum[1][rl]) + fmv[mi][q];
                out[(size_t)m * 64 + wc * 32 + lrow] = vb[mi][0][q] - ls;
                out[(size_t)m * 64 + wc * 32 + 16 + lrow] = vb[mi][1][q] - ls;
            }
        }
}

// ---------------- aggregation (R15 shape: 16 lanes/edge x uint2, 4 sub-slots) ----------
// fp8 gather source (128B/row); bdp = packed bf16 {b, dinv} (4B random access).
template <bool FUSE_AB, bool RAW_NT>
__global__ __launch_bounds__(256) void k_agg(const uint32_t* __restrict__ hf,
                                             const uint32_t* __restrict__ raw,
                                             const int* __restrict__ rp,
                                             const int* __restrict__ ecol,
                                             const float* __restrict__ av,
                                             const uint32_t* __restrict__ bdp,
                                             const float* __restrict__ dinv,
                                             uint32_t* __restrict__ hb_out,
                                             uint32_t* __restrict__ hf_out,
                                             const float* __restrict__ gw_next,
                                             const float* __restrict__ gb_next,
                                             float* __restrict__ av_out,
                                             uint32_t* __restrict__ bdp_out, int N) {
    int wid = threadIdx.x >> 6, lane = threadIdx.x & 63;
    int i = blockIdx.x * 4 + wid;
    if (i >= N) return;
    int iu = __builtin_amdgcn_readfirstlane(i);
    int p0 = __builtin_amdgcn_readfirstlane(rp[iu]);
    int p1 = __builtin_amdgcn_readfirstlane(rp[iu + 1]);
    float a_i = av[iu];
    float di = dinv[iu];
    const int lg = lane >> 4;   // edge sub-slot (4)
    const int ll = lane & 15;   // channel octet (16 x 8 ch)
    const char* hfp = (const char*)hf + (ll << 3);  // per-lane gather base (8B)

    // issue raw-row load EARLY so its latency hides under the gather loop
    uint32_t r0 = 0, r1 = 0, r2 = 0, r3 = 0;
    if (lane < 16) {
        const uint32_t* rpt = raw + (size_t)i * 64 + ll * 4;
        if (RAW_NT) {
            r0 = __builtin_nontemporal_load(rpt + 0);
            r1 = __builtin_nontemporal_load(rpt + 1);
            r2 = __builtin_nontemporal_load(rpt + 2);
            r3 = __builtin_nontemporal_load(rpt + 3);
        } else {
            r0 = rpt[0]; r1 = rpt[1]; r2 = rpt[2]; r3 = rpt[3];
        }
    }

    float acc[8];
#pragma unroll
    for (int j = 0; j < 8; ++j) acc[j] = 0.f;

#define FMA8F8(W, U)                                                   \
    {                                                                  \
        auto p01 = __builtin_amdgcn_cvt_pk_f32_fp8((U).x, false);      \
        auto p23 = __builtin_amdgcn_cvt_pk_f32_fp8((U).x, true);       \
        auto p45 = __builtin_amdgcn_cvt_pk_f32_fp8((U).y, false);      \
        auto p67 = __builtin_amdgcn_cvt_pk_f32_fp8((U).y, true);       \
        acc[0] = fmaf(W, p01[0], acc[0]); acc[1] = fmaf(W, p01[1], acc[1]); \
        acc[2] = fmaf(W, p23[0], acc[2]); acc[3] = fmaf(W, p23[1], acc[3]); \
        acc[4] = fmaf(W, p45[0], acc[4]); acc[5] = fmaf(W, p45[1], acc[5]); \
        acc[6] = fmaf(W, p67[0], acc[6]); acc[7] = fmaf(W, p67[1], acc[7]); \
    }

    for (int b0 = p0; b0 < p1; b0 += 64) {
        int cnt = min(64, p1 - b0);
        // Phase A: weights for this batch (pad lanes: w=0, c=0 -> L1-hot row 0)
        uint32_t wcp = 0u;
        if (lane < cnt) {
            int c = __builtin_nontemporal_load(&ecol[b0 + lane]);
            uint32_t t = bdp[c];
            float w = fast_tanh(a_i + bflo(t)) * bfhi(t);
            wcp = (f2bf(w) << 16) | (uint32_t)c;
        }
        // Phase B: 16-edge windows, 4 uint2 gathers in flight
        int cntp = (cnt + 15) & ~15;
        for (int k = 0; k < cntp; k += 16) {
            int kb = (k + lg) << 2;
            uint32_t wx0 = __builtin_amdgcn_ds_bpermute(kb, (int)wcp);
            uint32_t wx1 = __builtin_amdgcn_ds_bpermute(kb + 16, (int)wcp);
            uint32_t wx2 = __builtin_amdgcn_ds_bpermute(kb + 32, (int)wcp);
            uint32_t wx3 = __builtin_amdgcn_ds_bpermute(kb + 48, (int)wcp);
            uint2 u0 = *(const uint2*)(hfp + ((wx0 & 0xffffu) << 7));
            uint2 u1 = *(const uint2*)(hfp + ((wx1 & 0xffffu) << 7));
            uint2 u2 = *(const uint2*)(hfp + ((wx2 & 0xffffu) << 7));
            uint2 u3 = *(const uint2*)(hfp + ((wx3 & 0xffffu) << 7));
            float w0 = bfhi(wx0), w1 = bfhi(wx1), w2 = bfhi(wx2), w3 = bfhi(wx3);
            FMA8F8(w0, u0);
            FMA8F8(w1, u1);
            FMA8F8(w2, u2);
            FMA8F8(w3, u3);
        }
    }
#undef FMA8F8
    // reduce across the 4 edge sub-slots
#pragma unroll
    for (int j = 0; j < 8; ++j) {
        acc[j] += __shfl_xor(acc[j], 16);
        acc[j] += __shfl_xor(acc[j], 32);
    }
    // epilogue: lanes 0-15 own 8 channels each (ch = ll*8 + j)
    if (lane < 16) {
        float o[8];
        o[0] = EPSF * bflo(r0) + di * acc[0]; o[1] = EPSF * bfhi(r0) + di * acc[1];
        o[2] = EPSF * bflo(r1) + di * acc[2]; o[3] = EPSF * bfhi(r1) + di * acc[3];
        o[4] = EPSF * bflo(r2) + di * acc[4]; o[5] = EPSF * bfhi(r2) + di * acc[5];
        o[6] = EPSF * bflo(r3) + di * acc[6]; o[7] = EPSF * bfhi(r3) + di * acc[7];
        uint4 w4;
        w4.x = pack2(o[0], o[1]); w4.y = pack2(o[2], o[3]);
        w4.z = pack2(o[4], o[5]); w4.w = pack2(o[6], o[7]);
        *((uint4*)(hb_out + (size_t)i * 64) + ll) = w4;
        if (FUSE_AB) {
            // fp8 shadow for next layer's gather
            uint32_t pk8a = 0, pk8b = 0;
            pk8a = __builtin_amdgcn_cvt_pk_fp8_f32(o[0], o[1], pk8a, false);
            pk8a = __builtin_amdgcn_cvt_pk_fp8_f32(o[2], o[3], pk8a, true);
            pk8b = __builtin_amdgcn_cvt_pk_fp8_f32(o[4], o[5], pk8b, false);
            pk8b = __builtin_amdgcn_cvt_pk_fp8_f32(o[6], o[7], pk8b, true);
            *((uint2*)(hf_out + (size_t)i * 32) + ll) = make_uint2(pk8a, pk8b);
            // next-layer gate scalars
            float pa = 0.f, pb = 0.f;
#pragma unroll
            for (int j = 0; j < 8; ++j) {
                int ch = ll * 8 + j;
                pa = fmaf(o[j], gw_next[ch], pa);
                pb = fmaf(o[j], gw_next[128 + ch], pb);
            }
#pragma unroll
            for (int off = 1; off < 16; off <<= 1) {
                pa += __shfl_xor(pa, off);
                pb += __shfl_xor(pb, off);
            }
            if (ll == 0) {
                av_out[i] = pa + gb_next[0];
                bdp_out[i] = pack2(pb, di);
            }
        }
    }
}

extern "C" void kernel_launch(void* const* d_in, const int* in_sizes, int n_in,
                              void* d_out, int out_size, void* d_ws, size_t ws_size,
                              hipStream_t stream) {
    const float* x = (const float*)d_in[0];
    const int* ei = (const int*)d_in[1];
    const float* t1w = (const float*)d_in[2];
    const float* t1b = (const float*)d_in[3];
    const float* gw = (const float*)d_in[4];
    const float* gb = (const float*)d_in[5];
    const float* t2w = (const float*)d_in[6];
    const float* t2b = (const float*)d_in[7];
    float* out = (float*)d_out;

    const int INC = 256;
    const int N = in_sizes[0] / INC;
    const int E = in_sizes[1] / 2;
    const int NB = (N + NPB - 1) >> SHB;
    const int nblk = (E + CHUNK - 1) / CHUNK;
    const int nbb = (N + 3) / 4;

    char* ws = (char*)d_ws;
    auto alloc = [&](size_t bytes) {
        char* p = ws;
        ws += (bytes + 255) & ~(size_t)255;
        return p;
    };
    uint32_t* pk = (uint32_t*)alloc((size_t)E * 4);
    int* hist = (int*)alloc((size_t)NB * nblk * 4);
    int* btot = (int*)alloc((size_t)NB * 4);
    uint32_t* ebuf = (uint32_t*)alloc((size_t)E * 4);
    int* rp = (int*)alloc((size_t)(N + 1) * 4);
    float* dinv = (float*)alloc((size_t)N * 4);
    int* ecol = (int*)alloc((size_t)E * 4);
    float* av0 = (float*)alloc((size_t)N * 4);
    float* av1 = (float*)alloc((size_t)N * 4);
    uint32_t* bdp0 = (uint32_t*)alloc((size_t)N * 4);
    uint32_t* bdp1 = (uint32_t*)alloc((size_t)N * 4);
    uint32_t* hb0 = (uint32_t*)alloc((size_t)N * 64 * 4);
    uint32_t* hb1 = (uint32_t*)alloc((size_t)N * 64 * 4);
    uint32_t* hb2 = (uint32_t*)alloc((size_t)N * 64 * 4);
    uint32_t* hf0 = (uint32_t*)alloc((size_t)N * 32 * 4);
    uint32_t* hf1 = (uint32_t*)alloc((size_t)N * 32 * 4);

    // ---- CSR build ----
    k_pack<<<nblk, 256, 0, stream>>>(ei, E, pk, hist, nblk, NB);
    k_scanA<<<NB, 64, 0, stream>>>(hist, nblk, btot);
    k_binwrite<<<nblk, 256, 0, stream>>>(pk, E, hist, btot, ebuf, nblk, NB);
    k_csr<<<NB, 256, 0, stream>>>(ebuf, btot, rp, dinv, ecol, N, E, NB);

    // ---- hb0/hf0 = relu(x @ t1_w^T + t1_b) + layer-0 gate scalars ----
    k_gemm1<<<(N + 127) / 128, 256, 0, stream>>>(x, t1w, t1b, hb0, hf0,
                                                 gw + 0 * 256, gb, dinv, av0, bdp0, N);

    // ---- layer 0: gather hf0 -> hb1 + hf1, fused layer-1 gate scalars ----
    k_agg<true, false><<<nbb, 256, 0, stream>>>(
        hf0, hb0, rp, ecol, av0, bdp0, dinv, hb1, hf1,
        gw + 1 * 256, gb + 1, av1, bdp1, N);
    // ---- layer 1: gather hf1 -> hb2 (raw = hb0, nontemporal) ----
    k_agg<false, true><<<nbb, 256, 0, stream>>>(
        hf1, hb0, rp, ecol, av1, bdp1, dinv, hb2, nullptr,
        nullptr, nullptr, nullptr, nullptr, N);

    // ---- out = log_softmax(hb2 @ t2_w^T + t2_b) ----
    k_gemm2<<<(N + 127) / 128, 256, 0, stream>>>(hb2, t2w, t2b, out, N);
}